// Round 1
// baseline (138.563 us; speedup 1.0000x reference)
//
#include <hip/hip_runtime.h>
#include <hip/hip_fp16.h>
#include <math.h>
#include <stdint.h>
#include <stddef.h>

#define NLEVELS 16
#define HSIZE   32768
#define LOGH    15
#define RANKK   4
#define PRIME1  2654435761u
#define PRIME2  805459861u

#define BLK2 1024
#define PPB  8192   // points per encode block

struct ResArr { float v[NLEVELS]; };

// ---------------- Kernel 1: materialize LoRA tables as packed fp16x2 ----------------
// T[l*HSIZE + s] = pack_half2( sum_r A[l,s,r]*B[l,r,0], sum_r A[l,s,r]*B[l,r,1] )
__global__ void build_tables_k(const float* __restrict__ A, const float* __restrict__ B,
                               uint32_t* __restrict__ T) {
    int i = blockIdx.x * blockDim.x + threadIdx.x;
    if (i >= NLEVELS * HSIZE) return;
    int l = i >> LOGH;
    const float4 a = *reinterpret_cast<const float4*>(A + (size_t)i * RANKK);
    const float* b = B + l * (RANKK * 2);   // [r][f]
    float f0 = a.x * b[0] + a.y * b[2] + a.z * b[4] + a.w * b[6];
    float f1 = a.x * b[1] + a.y * b[3] + a.z * b[5] + a.w * b[7];
    __half2 h = __floats2half2_rn(f0, f1);
    T[i] = *reinterpret_cast<uint32_t*>(&h);
}

// ---------------- Kernel 2: per-(level, chunk) encode with LDS-resident table -------
// grid.x = chunks*16 ; level = bx & 15, chunk = bx >> 4
// directOut=0: dst_base = outT, write outT[l*nPoints*2 + n*2 + f]   (coalesced)
// directOut=1: dst_base = out,  write out[n*32 + 2l + f]            (fallback layout)
__global__ __launch_bounds__(BLK2)
void encode_level_k(const float* __restrict__ x, const uint32_t* __restrict__ T,
                    float* __restrict__ dst_base, int nPoints, int directOut,
                    ResArr res) {
    __shared__ uint32_t lds[HSIZE];          // 128 KiB (gfx950 LDS = 160 KiB)
    const int l     = blockIdx.x & (NLEVELS - 1);
    const int chunk = blockIdx.x >> 4;

    // stage the whole level table into LDS (16B per lane per iter)
    const uint32_t* Tl = T + (size_t)l * HSIZE;
    for (int i = threadIdx.x; i < HSIZE / 4; i += BLK2) {
        reinterpret_cast<uint4*>(lds)[i] = reinterpret_cast<const uint4*>(Tl)[i];
    }
    __syncthreads();

    const float r = res.v[l];
    const int base = chunk * PPB;
    float* dst;
    size_t stride;
    if (directOut) { dst = dst_base + 2 * l;                      stride = 32; }
    else           { dst = dst_base + (size_t)l * nPoints * 2;    stride = 2;  }

    for (int k = 0; k < PPB; k += BLK2) {
        int n = base + k + (int)threadIdx.x;
        if (n >= nPoints) break;
        // bit-exact replication of reference fp32 math
        float xn0 = (x[3 * n + 0] + 1.0f) * 0.5f;   // (x+range)/(2*range), /2 exact
        float xn1 = (x[3 * n + 1] + 1.0f) * 0.5f;
        float xn2 = (x[3 * n + 2] + 1.0f) * 0.5f;
        float xl0 = xn0 * r, xl1 = xn1 * r, xl2 = xn2 * r;
        float fl0 = floorf(xl0), fl1 = floorf(xl1), fl2 = floorf(xl2);
        float w0 = xl0 - fl0, w1 = xl1 - fl1, w2 = xl2 - fl2;
        uint32_t i0 = (uint32_t)fl0, i1 = (uint32_t)fl1, i2 = (uint32_t)fl2;

        uint32_t hx0 = i0,          hx1 = i0 + 1u;
        uint32_t hy0 = i1 * PRIME1, hy1 = hy0 + PRIME1;   // (i1+1)*P1 mod 2^32
        uint32_t hz0 = i2 * PRIME2, hz1 = hz0 + PRIME2;

        float w0a = 1.0f - w0, w1a = 1.0f - w1, w2a = 1.0f - w2;
        float wxy00 = w0a * w1a, wxy10 = w0 * w1a, wxy01 = w0a * w1, wxy11 = w0 * w1;

        float acc0 = 0.0f, acc1 = 0.0f;
#pragma unroll
        for (int c = 0; c < 8; ++c) {
            uint32_t h = ((c & 1) ? hx1 : hx0) ^ ((c & 2) ? hy1 : hy0) ^ ((c & 4) ? hz1 : hz0);
            uint32_t pk = lds[h & (HSIZE - 1)];
            __half2 h2 = *reinterpret_cast<__half2*>(&pk);
            float2 f = __half22float2(h2);
            float wxy = (c & 2) ? ((c & 1) ? wxy11 : wxy01) : ((c & 1) ? wxy10 : wxy00);
            float wc = wxy * ((c & 4) ? w2 : w2a);
            acc0 = fmaf(f.x, wc, acc0);
            acc1 = fmaf(f.y, wc, acc1);
        }
        *reinterpret_cast<float2*>(dst + (size_t)n * stride) = make_float2(acc0, acc1);
    }
}

// ---------------- Kernel 3: transpose-merge outT[l][n][2] -> out[n][32] -------------
__global__ void merge_k(const float* __restrict__ outT, float* __restrict__ out, int nPoints) {
    int n = blockIdx.x * blockDim.x + threadIdx.x;
    if (n >= nPoints) return;
    const float2* src = reinterpret_cast<const float2*>(outT);
    float4 o[8];
#pragma unroll
    for (int q = 0; q < 8; ++q) {
        float2 a = src[(size_t)(2 * q)     * nPoints + n];   // coalesced per level
        float2 b = src[(size_t)(2 * q + 1) * nPoints + n];
        o[q] = make_float4(a.x, a.y, b.x, b.y);
    }
    float4* dstv = reinterpret_cast<float4*>(out + (size_t)n * 32);
#pragma unroll
    for (int q = 0; q < 8; ++q) dstv[q] = o[q];
}

// ---------------- Fallback: on-the-fly LoRA dequant, global gather (tiny ws) --------
__global__ void encode_fallback_k(const float* __restrict__ x, const float* __restrict__ A,
                                  const float* __restrict__ B, float* __restrict__ out,
                                  int nPoints, ResArr res) {
    int n = blockIdx.x * blockDim.x + threadIdx.x;
    if (n >= nPoints) return;
    float xn0 = (x[3 * n + 0] + 1.0f) * 0.5f;
    float xn1 = (x[3 * n + 1] + 1.0f) * 0.5f;
    float xn2 = (x[3 * n + 2] + 1.0f) * 0.5f;
    for (int l = 0; l < NLEVELS; ++l) {
        float r = res.v[l];
        float xl0 = xn0 * r, xl1 = xn1 * r, xl2 = xn2 * r;
        float fl0 = floorf(xl0), fl1 = floorf(xl1), fl2 = floorf(xl2);
        float w0 = xl0 - fl0, w1 = xl1 - fl1, w2 = xl2 - fl2;
        uint32_t i0 = (uint32_t)fl0, i1 = (uint32_t)fl1, i2 = (uint32_t)fl2;
        uint32_t hx0 = i0,          hx1 = i0 + 1u;
        uint32_t hy0 = i1 * PRIME1, hy1 = hy0 + PRIME1;
        uint32_t hz0 = i2 * PRIME2, hz1 = hz0 + PRIME2;
        float w0a = 1.0f - w0, w1a = 1.0f - w1, w2a = 1.0f - w2;
        float wxy00 = w0a * w1a, wxy10 = w0 * w1a, wxy01 = w0a * w1, wxy11 = w0 * w1;
        const float* b = B + l * 8;
        float b00 = b[0], b01 = b[1], b10 = b[2], b11 = b[3];
        float b20 = b[4], b21 = b[5], b30 = b[6], b31 = b[7];
        float acc0 = 0.0f, acc1 = 0.0f;
#pragma unroll
        for (int c = 0; c < 8; ++c) {
            uint32_t h = ((c & 1) ? hx1 : hx0) ^ ((c & 2) ? hy1 : hy0) ^ ((c & 4) ? hz1 : hz0);
            uint32_t idx = h & (HSIZE - 1);
            float4 a = *reinterpret_cast<const float4*>(A + ((size_t)l * HSIZE + idx) * RANKK);
            float fe0 = a.x * b00 + a.y * b10 + a.z * b20 + a.w * b30;
            float fe1 = a.x * b01 + a.y * b11 + a.z * b21 + a.w * b31;
            float wxy = (c & 2) ? ((c & 1) ? wxy11 : wxy01) : ((c & 1) ? wxy10 : wxy00);
            float wc = wxy * ((c & 4) ? w2 : w2a);
            acc0 = fmaf(fe0, wc, acc0);
            acc1 = fmaf(fe1, wc, acc1);
        }
        out[(size_t)n * 32 + 2 * l + 0] = acc0;
        out[(size_t)n * 32 + 2 * l + 1] = acc1;
    }
}

extern "C" void kernel_launch(void* const* d_in, const int* in_sizes, int n_in,
                              void* d_out, int out_size, void* d_ws, size_t ws_size,
                              hipStream_t stream) {
    const float* x = (const float*)d_in[0];
    const float* A = (const float*)d_in[1];
    const float* B = (const float*)d_in[2];
    float* out = (float*)d_out;
    int nPoints = in_sizes[0] / 3;

    // Replicate numpy's resolution ladder bit-exactly in host double libm:
    // b = exp((log(512)-log(16))/15); res_l = float(floor(16 * b**l))
    ResArr ra;
    {
        double b = exp((log(512.0) - log(16.0)) / 15.0);
        for (int l = 0; l < NLEVELS; ++l)
            ra.v[l] = (float)floor(16.0 * pow(b, (double)l));
    }

    const size_t tblBytes  = (size_t)NLEVELS * HSIZE * sizeof(uint32_t);        // 2 MiB
    const size_t outTBytes = (size_t)NLEVELS * (size_t)nPoints * 2 * sizeof(float); // 64 MiB

    if (ws_size >= tblBytes) {
        uint32_t* T = (uint32_t*)d_ws;
        int nb1 = (NLEVELS * HSIZE + 255) / 256;
        build_tables_k<<<nb1, 256, 0, stream>>>(A, B, T);
        int chunks = (nPoints + PPB - 1) / PPB;
        if (ws_size >= tblBytes + outTBytes) {
            float* outT = (float*)((char*)d_ws + tblBytes);
            encode_level_k<<<chunks * NLEVELS, BLK2, 0, stream>>>(x, T, outT, nPoints, 0, ra);
            merge_k<<<(nPoints + 255) / 256, 256, 0, stream>>>(outT, out, nPoints);
        } else {
            // not enough scratch for the transposed intermediate: write final layout directly
            encode_level_k<<<chunks * NLEVELS, BLK2, 0, stream>>>(x, T, out, nPoints, 1, ra);
        }
    } else {
        encode_fallback_k<<<(nPoints + 255) / 256, 256, 0, stream>>>(x, A, B, out, nPoints, ra);
    }
}